// Round 13
// baseline (61.933 us; speedup 1.0000x reference)
//
#include <hip/hip_runtime.h>
#include <hip/hip_bf16.h>

// Problem constants
static constexpr int FEAT_  = 3136;   // K of GEMM1
static constexpr int KSTEPS = 98;     // 3136 / 32
static constexpr int RSTR   = 300;    // x row stride (proposals per batch)
static constexpr int SROWS  = 128;    // SELECTED_PROPOSAL
static constexpr int HID    = 64;     // hidden
static constexpr int NCLS   = 21;     // classes
static constexpr int BM     = 32;     // rows per block
static constexpr int PACKB  = 32;     // pack blocks (blockIdx 0..31, dispatched first)
static constexpr int NFRAG  = KSTEPS * 4 * 64;   // 25088
static constexpr int MAINB  = (64 * SROWS) / BM; // 256 main blocks

typedef __attribute__((ext_vector_type(8))) short bf16x8;
typedef __attribute__((ext_vector_type(4))) float f32x4;

// W1 pre-packed in MFMA B-fragment order with the dense-line k-permutation:
//   frag elem j<4 : k = ks*32 + g*4 + j        (g = lane>>4)
//   frag elem j>=4: k = ks*32 + 16 + g*4 + j-4
__device__ bf16x8 g_w1p[NFRAG];
__device__ int g_done;        // packs completed (zero-init; reset each launch)
__device__ int g_main_done;   // mains completed (zero-init; reset each launch)

__device__ __forceinline__ short f2bf(float f) {
    union { float f; unsigned u; } v; v.f = f;
    unsigned r = v.u + 0x7fffu + ((v.u >> 16) & 1u);   // round-to-nearest-even
    return (short)(r >> 16);
}

// Single fused dispatch: blocks 0..31 pack W1 then signal; 256 main blocks
// spin (s_sleep) on the flag before their K-loop. Pack blocks are FIRST in
// the grid so they are always scheduled -> no deadlock regardless of
// residency. Flags self-reset: the 256th main completion zeroes both.
__global__ __launch_bounds__(512, 2) void fused_all(
    const float* __restrict__ x,  const float* __restrict__ W1,
    const float* __restrict__ b1, const float* __restrict__ W2,
    const float* __restrict__ b2, const int* __restrict__ keep,
    float* __restrict__ out)
{
    const int tid = threadIdx.x;

    // ---------------- pack blocks ----------------
    if (blockIdx.x < PACKB) {
        for (int t = blockIdx.x * 512 + tid; t < NFRAG; t += PACKB * 512) {
            int lane = t & 63;
            int nt   = (t >> 6) & 3;
            int ks   = t >> 8;
            int col  = nt * 16 + (lane & 15);
            int g    = lane >> 4;
            int k0   = ks * 32 + g * 4;
            bf16x8 v;
            #pragma unroll
            for (int j = 0; j < 4; ++j) v[j]     = f2bf(W1[(k0 + j) * HID + col]);
            #pragma unroll
            for (int j = 0; j < 4; ++j) v[4 + j] = f2bf(W1[(k0 + 16 + j) * HID + col]);
            g_w1p[t] = v;
        }
        __threadfence();                       // make w1p visible device-wide
        __syncthreads();
        if (tid == 0) atomicAdd(&g_done, 1);   // device-scope by default
        return;
    }

    // ---------------- main blocks ----------------
    const int bid  = blockIdx.x - PACKB;       // 0..255
    const int lane = tid & 63;
    const int wv   = tid >> 6;                 // 0..7 = K-part
    const int row_base = bid * BM;             // flat (b*128 + s) row
    const int b      = row_base >> 7;
    const int s_base = row_base & 127;

    float* outp = out + row_base * NCLS;
    const int limit = min(keep[b], SROWS);

    // Whole 32-row group masked: zeros, then register completion (no spin
    // needed -- the 256th increment necessarily follows all unmasked spins).
    if (s_base >= limit) {
        for (int i = tid; i < BM * NCLS; i += 512) outp[i] = 0.f;
        __syncthreads();
        if (tid == 0) {
            int n = atomicAdd(&g_main_done, 1);
            if (n == MAINB - 1) {
                __hip_atomic_store(&g_main_done, 0, __ATOMIC_RELAXED, __HIP_MEMORY_SCOPE_AGENT);
                __hip_atomic_store(&g_done, 0, __ATOMIC_RELAXED, __HIP_MEMORY_SCOPE_AGENT);
            }
        }
        return;
    }

    __shared__ float hp[8][BM][HID + 1];   // per-wave K-partial sums (66.5 KB)
    __shared__ float hf[BM][HID + 2];      // reduced h
    __shared__ float w2s[HID * NCLS];

    // Overlap with pack: stage W2, compute addresses, THEN wait on the flag.
    for (int i = tid; i < HID * NCLS; i += 512) w2s[i] = W2[i];

    const int ks0 = (wv * KSTEPS) >> 3;
    const int ks1 = ((wv + 1) * KSTEPS) >> 3;

    const int g = lane >> 4;            // k-group
    const int r = lane & 15;            // row within m-tile / B col
    const int row0 = min(s_base + r,      limit - 1);
    const int row1 = min(s_base + 16 + r, limit - 1);
    const float* xp0 = x + (b * RSTR + row0) * FEAT_ + g * 4;
    const float* xp1 = x + (b * RSTR + row1) * FEAT_ + g * 4;
    const bf16x8* wp = g_w1p + lane;    // frag (ks*4+nq)*64 + lane

    // Wait for pack (early blocks spin ~pack duration; s_sleep keeps it cool).
    if (tid == 0) {
        while (__hip_atomic_load(&g_done, __ATOMIC_ACQUIRE, __HIP_MEMORY_SCOPE_AGENT) < PACKB)
            __builtin_amdgcn_s_sleep(4);
        __threadfence();
    }
    __syncthreads();   // also covers the w2s staging

    f32x4 a00 = {0,0,0,0}, a01 = {0,0,0,0}, a02 = {0,0,0,0}, a03 = {0,0,0,0};
    f32x4 a10 = {0,0,0,0}, a11 = {0,0,0,0}, a12 = {0,0,0,0}, a13 = {0,0,0,0};

    #pragma unroll 2
    for (int ks = ks0; ks < ks1; ++ks) {
        // Two dense 64B-line loads per row: floats [g*4, g*4+4) and +16.
        float4 p0a = *(const float4*)(xp0 + ks * 32);
        float4 p0b = *(const float4*)(xp0 + ks * 32 + 16);
        float4 p1a = *(const float4*)(xp1 + ks * 32);
        float4 p1b = *(const float4*)(xp1 + ks * 32 + 16);
        bf16x8 bv0 = wp[(ks * 4 + 0) * 64];
        bf16x8 bv1 = wp[(ks * 4 + 1) * 64];
        bf16x8 bv2 = wp[(ks * 4 + 2) * 64];
        bf16x8 bv3 = wp[(ks * 4 + 3) * 64];
        bf16x8 af0, af1;
        af0[0]=f2bf(p0a.x); af0[1]=f2bf(p0a.y); af0[2]=f2bf(p0a.z); af0[3]=f2bf(p0a.w);
        af0[4]=f2bf(p0b.x); af0[5]=f2bf(p0b.y); af0[6]=f2bf(p0b.z); af0[7]=f2bf(p0b.w);
        af1[0]=f2bf(p1a.x); af1[1]=f2bf(p1a.y); af1[2]=f2bf(p1a.z); af1[3]=f2bf(p1a.w);
        af1[4]=f2bf(p1b.x); af1[5]=f2bf(p1b.y); af1[6]=f2bf(p1b.z); af1[7]=f2bf(p1b.w);
        a00 = __builtin_amdgcn_mfma_f32_16x16x32_bf16(af0, bv0, a00, 0, 0, 0);
        a01 = __builtin_amdgcn_mfma_f32_16x16x32_bf16(af0, bv1, a01, 0, 0, 0);
        a02 = __builtin_amdgcn_mfma_f32_16x16x32_bf16(af0, bv2, a02, 0, 0, 0);
        a03 = __builtin_amdgcn_mfma_f32_16x16x32_bf16(af0, bv3, a03, 0, 0, 0);
        a10 = __builtin_amdgcn_mfma_f32_16x16x32_bf16(af1, bv0, a10, 0, 0, 0);
        a11 = __builtin_amdgcn_mfma_f32_16x16x32_bf16(af1, bv1, a11, 0, 0, 0);
        a12 = __builtin_amdgcn_mfma_f32_16x16x32_bf16(af1, bv2, a12, 0, 0, 0);
        a13 = __builtin_amdgcn_mfma_f32_16x16x32_bf16(af1, bv3, a13, 0, 0, 0);
    }

    // D layout: col = lane&15 (+16*nq), row-in-tile = g*4 + reg (+16*m)
    #pragma unroll
    for (int rr = 0; rr < 4; ++rr) {
        const int mr0 = g * 4 + rr, mr1 = 16 + g * 4 + rr;
        hp[wv][mr0][r     ] = a00[rr];
        hp[wv][mr0][r + 16] = a01[rr];
        hp[wv][mr0][r + 32] = a02[rr];
        hp[wv][mr0][r + 48] = a03[rr];
        hp[wv][mr1][r     ] = a10[rr];
        hp[wv][mr1][r + 16] = a11[rr];
        hp[wv][mr1][r + 32] = a12[rr];
        hp[wv][mr1][r + 48] = a13[rr];
    }
    __syncthreads();

    // Reduce over the 8 K-partials, add b1, leaky relu #1
    for (int e = tid; e < BM * HID; e += 512) {
        int row = e >> 6, col = e & 63;
        float v = b1[col];
        #pragma unroll
        for (int p = 0; p < 8; ++p) v += hp[p][row][col];
        hf[row][col] = (v >= 0.f) ? v : 0.1f * v;
    }
    __syncthreads();

    // GEMM2: [32 x 64] @ [64 x 21] + b2, leaky, keep_count mask
    for (int idx = tid; idx < BM * NCLS; idx += 512) {
        int rI = idx / NCLS;
        int c  = idx - rI * NCLS;
        float a2 = b2[c];
        #pragma unroll 8
        for (int col = 0; col < HID; ++col)
            a2 += hf[rI][col] * w2s[col * NCLS + c];
        a2 = (a2 >= 0.f) ? a2 : 0.1f * a2;        // leaky relu #2
        outp[idx] = (s_base + rI < limit) ? a2 : 0.f;
    }

    __syncthreads();
    if (tid == 0) {
        int n = atomicAdd(&g_main_done, 1);
        if (n == MAINB - 1) {                      // last main: reset flags
            __hip_atomic_store(&g_main_done, 0, __ATOMIC_RELAXED, __HIP_MEMORY_SCOPE_AGENT);
            __hip_atomic_store(&g_done, 0, __ATOMIC_RELAXED, __HIP_MEMORY_SCOPE_AGENT);
        }
    }
}

extern "C" void kernel_launch(void* const* d_in, const int* in_sizes, int n_in,
                              void* d_out, int out_size, void* d_ws, size_t ws_size,
                              hipStream_t stream) {
    const float* x    = (const float*)d_in[0];
    const float* W1   = (const float*)d_in[1];
    const float* b1   = (const float*)d_in[2];
    const float* W2   = (const float*)d_in[3];
    const float* b2   = (const float*)d_in[4];
    const int*   keep = (const int*)d_in[5];
    float* out = (float*)d_out;

    hipLaunchKernelGGL(fused_all, dim3(PACKB + MAINB), dim3(512), 0, stream,
                       x, W1, b1, W2, b2, keep, out);
}